// Round 9
// baseline (1223.844 us; speedup 1.0000x reference)
//
#include <hip/hip_runtime.h>

// ImplicitField: B=4, C=32, G=64, N=131072, HID=128
//
// R9: retreat to the PROVEN f32-VALU design (R1 passed @4.88e-4) and fix its
// diagnosed bottleneck: R1's h1[128] spilled to scratch (VGPR_Count=96,
// VALUBusy 47.7%). Here h1 lives in LDS, k-major [128][64] so thread t owns
// column t: writes/reads are lane-consecutive (conflict-free) and strictly
// thread-private (race-impossible, no barrier). All other paths are R1 code.
// The MFMA arc (R5-R8) is abandoned: 4-term-split R8 proved a structural bug
// (error ROSE to 1.04e-1 with near-exact numerics); not findable by audit.
//
//  k_ft32 : features [B,C,z,y,x] -> ft [B,z,y,x,C] f32 (128 MiB, R1-proven)
//  k_tw2  : w2 [j][k] -> w2t [k][j] (R1-proven)
//  k_field: 64 thr/block, one point per lane:
//    gather 8 corners x 8 float4; layer1 fully unrolled, h1 -> LDS column;
//    layer2 in 8 chunks of 16 acc regs, k statically unrolled reading own
//    LDS column; layer3 fused. Weights via wave-uniform s_loads.

static constexpr int    kB = 4, kN = 131072;
static constexpr size_t kFtElems = (size_t)4 * 64 * 64 * 64 * 32;   // 33,554,432
static constexpr size_t kFtBytes = kFtElems * sizeof(float);        // 134,217,728

// ---------- prep 1: features f32 [B,C,64,64,64] -> f32 [B,64,64,64,C] ----------
__global__ __launch_bounds__(256) void k_ft32(const float* __restrict__ f,
                                              float* __restrict__ ft)
{
    __shared__ float tile[32][65];            // +1 pad: conflict-free col reads
    const int blk = blockIdx.x;
    const int b = blk >> 12, z = (blk >> 6) & 63, y = blk & 63, t = threadIdx.x;

    const int x = t & 63, c0 = t >> 6;
    const size_t ibase = (size_t)b * 8388608 + (size_t)z * 4096 + (size_t)y * 64;
    #pragma unroll
    for (int cc = 0; cc < 8; ++cc) {
        const int c = c0 + cc * 4;
        tile[c][x] = f[ibase + (size_t)c * 262144 + x];
    }
    __syncthreads();

    const size_t obase = ((size_t)b * 262144 + (size_t)z * 4096 + (size_t)y * 64) * 32;
    const int c  = t & 31;
    const int x0 = t >> 5;                    // 0..7
    #pragma unroll
    for (int xo = 0; xo < 8; ++xo) {
        const int xx = x0 + xo * 8;
        ft[obase + (size_t)xx * 32 + c] = tile[c][xx];
    }
}

// ---------- prep 2: w2 [j][k] -> w2t [k][j] ----------
__global__ __launch_bounds__(256) void k_tw2(const float* __restrict__ w2,
                                             float* __restrict__ w2t)
{
    const int i = blockIdx.x * 256 + threadIdx.x;   // 0..16383; i = k*128 + j
    w2t[i] = w2[(i & 127) * 128 + (i >> 7)];
}

// ---------- main ----------
__global__ __launch_bounds__(64) void k_field(
    const float* __restrict__ ft, const float* __restrict__ w2t,
    const float* __restrict__ points,
    const float* __restrict__ w1, const float* __restrict__ b1,
    const float* __restrict__ b2,
    const float* __restrict__ w3, const float* __restrict__ b3,
    float* __restrict__ dens)
{
    __shared__ float h1s[128][64];            // k-major: thread t owns column t
    const int t = threadIdx.x;                // 0..63
    const int g = blockIdx.x * 64 + t;        // point id, 0..524287
    const int b = g >> 17;

    const float* pp = points + (size_t)g * 3;
    const float px = pp[0], py = pp[1], pz = pp[2];

    // reference: g=(p+1)/2 then pixel=((g+1)/2)*(dim-1) => (0.25p+0.75)*63
    const float fx = (0.25f * px + 0.75f) * 63.0f;
    const float fy = (0.25f * py + 0.75f) * 63.0f;
    const float fz = (0.25f * pz + 0.75f) * 63.0f;
    const float xf = floorf(fx), yf = floorf(fy), zf = floorf(fz);
    const float wx = fx - xf, wy = fy - yf, wz = fz - zf;
    int ix0 = (int)xf; ix0 = ix0 < 0 ? 0 : (ix0 > 63 ? 63 : ix0);
    int iy0 = (int)yf; iy0 = iy0 < 0 ? 0 : (iy0 > 63 ? 63 : iy0);
    int iz0 = (int)zf; iz0 = iz0 < 0 ? 0 : (iz0 > 63 ? 63 : iz0);
    const int ix1 = ix0 + 1 > 63 ? 63 : ix0 + 1;
    const int iy1 = iy0 + 1 > 63 ? 63 : iy0 + 1;
    const int iz1 = iz0 + 1 > 63 ? 63 : iz0 + 1;

    // ---- trilinear gather: 8 corners, each 32 contiguous channels ----
    float feat[32];
    #pragma unroll
    for (int c = 0; c < 32; ++c) feat[c] = 0.0f;

    const size_t vb = (size_t)b * 262144;
    #pragma unroll
    for (int corner = 0; corner < 8; ++corner) {
        const int dz = corner >> 2, dy = (corner >> 1) & 1, dx = corner & 1;
        const int iz = dz ? iz1 : iz0;
        const int iy = dy ? iy1 : iy0;
        const int ix = dx ? ix1 : ix0;
        const float w = (dz ? wz : 1.0f - wz) *
                        (dy ? wy : 1.0f - wy) *
                        (dx ? wx : 1.0f - wx);
        const float4* vp = reinterpret_cast<const float4*>(
            ft + ((vb + (size_t)iz * 4096 + (size_t)iy * 64 + (size_t)ix) << 5));
        #pragma unroll
        for (int q = 0; q < 8; ++q) {
            const float4 v = vp[q];
            feat[q * 4 + 0] = fmaf(w, v.x, feat[q * 4 + 0]);
            feat[q * 4 + 1] = fmaf(w, v.y, feat[q * 4 + 1]);
            feat[q * 4 + 2] = fmaf(w, v.z, feat[q * 4 + 2]);
            feat[q * 4 + 3] = fmaf(w, v.w, feat[q * 4 + 3]);
        }
    }

    // ---- layer 1: h1[j] = relu(W1 x + b1) -> LDS column t ----
    #pragma unroll
    for (int j = 0; j < 128; ++j) {
        const float* wr = w1 + j * 35;        // uniform address -> s_load
        float a = b1[j];
        a = fmaf(wr[0], px, a);
        a = fmaf(wr[1], py, a);
        a = fmaf(wr[2], pz, a);
        #pragma unroll
        for (int c = 0; c < 32; ++c) a = fmaf(wr[3 + c], feat[c], a);
        h1s[j][t] = fmaxf(a, 0.0f);
    }

    // ---- layer 2 + 3 fused: h2 chunks of 16, dot with w3 immediately ----
    float acc_out = b3[0];
    #pragma unroll 1
    for (int jc = 0; jc < 8; ++jc) {          // dynamic: bounds code size
        const float* wt = w2t + jc * 16;      // w2t[k][j]: 16 contiguous j per k
        float acc[16];
        #pragma unroll
        for (int jj = 0; jj < 16; ++jj) acc[jj] = b2[jc * 16 + jj];
        #pragma unroll
        for (int k = 0; k < 128; ++k) {       // static k: own LDS column
            const float h = h1s[k][t];
            #pragma unroll
            for (int jj = 0; jj < 16; ++jj)
                acc[jj] = fmaf(wt[(size_t)k * 128 + jj], h, acc[jj]);
        }
        #pragma unroll
        for (int jj = 0; jj < 16; ++jj)
            acc_out = fmaf(w3[jc * 16 + jj], fmaxf(acc[jj], 0.0f), acc_out);
    }

    dens[g] = acc_out;
}

extern "C" void kernel_launch(void* const* d_in, const int* in_sizes, int n_in,
                              void* d_out, int out_size, void* d_ws, size_t ws_size,
                              hipStream_t stream)
{
    const float* features = (const float*)d_in[0];
    const float* points   = (const float*)d_in[1];
    const float* w1 = (const float*)d_in[2];
    const float* b1 = (const float*)d_in[3];
    const float* w2 = (const float*)d_in[4];
    const float* b2 = (const float*)d_in[5];
    const float* w3 = (const float*)d_in[6];
    const float* b3 = (const float*)d_in[7];

    char* wsb = (char*)d_ws;
    float* ft32 = (float*)wsb;                      // 128 MiB
    float* w2t  = (float*)(wsb + kFtBytes);         // 64 KiB (R1-proven footprint)

    float* out_points = (float*)d_out;
    float* out_dens   = (float*)d_out + (size_t)kB * kN * 3;

    hipMemcpyAsync(out_points, points, (size_t)kB * kN * 3 * sizeof(float),
                   hipMemcpyDeviceToDevice, stream);

    k_ft32<<<16384, 256, 0, stream>>>(features, ft32);
    k_tw2<<<64, 256, 0, stream>>>(w2, w2t);
    k_field<<<8192, 64, 0, stream>>>(ft32, w2t, points, w1, b1, b2, w3, b3,
                                     out_dens);
}